// Round 1
// baseline (3405.087 us; speedup 1.0000x reference)
//
#include <hip/hip_runtime.h>

#define N_ATOMS 100000
#define N_BONDS 200000
#define MAX_NB 6
#define HIDDEN 256
#define DEPTH 6
#define ATOM_FDIM 39
#define BOND_FDIM 11
#define WNODE_COLS (HIDDEN + BOND_FDIM)  // 267

// ---------------------------------------------------------------------------
// init: Hn = h0 = relu(fatoms @ W_nin.T)
//       base = h0 + (sum_nb fbonds[aoutgraph[a,nb]]) @ W_f.T
// one block (256 threads) per atom; thread t owns hidden channel t.
// ---------------------------------------------------------------------------
__global__ __launch_bounds__(256) void init_kernel(
    const float* __restrict__ fatoms,
    const float* __restrict__ fbonds,
    const int* __restrict__ aoutgraph,
    const float* __restrict__ W_nin,
    const float* __restrict__ W_node,
    float* __restrict__ Hn,
    float* __restrict__ base) {
  int a = blockIdx.x;
  int t = threadIdx.x;
  __shared__ float fa[ATOM_FDIM];
  __shared__ float fbsum[BOND_FDIM];
  if (t < ATOM_FDIM) fa[t] = fatoms[a * ATOM_FDIM + t];
  if (t < BOND_FDIM) {
    float s = 0.f;
#pragma unroll
    for (int nb = 0; nb < MAX_NB; ++nb) {
      int b = aoutgraph[a * MAX_NB + nb];
      s += fbonds[b * BOND_FDIM + t];
    }
    fbsum[t] = s;
  }
  __syncthreads();
  float h0 = 0.f;
  const float* wr = W_nin + t * ATOM_FDIM;
#pragma unroll
  for (int k = 0; k < ATOM_FDIM; ++k) h0 += fa[k] * wr[k];
  h0 = fmaxf(h0, 0.f);
  float fb = 0.f;
  const float* wn = W_node + t * WNODE_COLS + HIDDEN;
#pragma unroll
  for (int k = 0; k < BOND_FDIM; ++k) fb += fbsum[k] * wn[k];
  Hn[a * HIDDEN + t] = h0;
  base[a * HIDDEN + t] = h0 + fb;
}

// ---------------------------------------------------------------------------
// gemm: Hproj[a][h] = sum_k Hn[a][k] * W_node[h*267 + k]  (W_h part)
// fp32 tiled: BM=64, BN=64, BK=16, 256 threads, 4x4 micro-tile per thread.
// ---------------------------------------------------------------------------
#define BM 64
#define BN 64
#define BK 16

__global__ __launch_bounds__(256) void gemm_kernel(
    const float* __restrict__ A,   // Hn [M][256]
    const float* __restrict__ W,   // W_node [256][267]
    float* __restrict__ C) {       // Hproj [M][256]
  __shared__ float As[BK][BM + 1];
  __shared__ float Bs[BK][BN + 1];
  int m0 = blockIdx.x * BM;
  int n0 = blockIdx.y * BN;
  int tid = threadIdx.x;
  int tx = tid & 15, ty = tid >> 4;
  float acc[4][4] = {};
  for (int k0 = 0; k0 < HIDDEN; k0 += BK) {
#pragma unroll
    for (int l = 0; l < 4; ++l) {
      int id = tid + l * 256;
      int r = id >> 4, c = id & 15;
      int row = m0 + r;
      As[c][r] = (row < N_ATOMS) ? A[row * HIDDEN + k0 + c] : 0.f;
    }
#pragma unroll
    for (int l = 0; l < 4; ++l) {
      int id = tid + l * 256;
      int r = id >> 4, c = id & 15;
      Bs[c][r] = W[(n0 + r) * WNODE_COLS + k0 + c];
    }
    __syncthreads();
#pragma unroll
    for (int k = 0; k < BK; ++k) {
      float av[4], bv[4];
#pragma unroll
      for (int i = 0; i < 4; ++i) av[i] = As[k][ty * 4 + i];
#pragma unroll
      for (int j = 0; j < 4; ++j) bv[j] = Bs[k][tx * 4 + j];
#pragma unroll
      for (int i = 0; i < 4; ++i)
#pragma unroll
        for (int j = 0; j < 4; ++j) acc[i][j] += av[i] * bv[j];
    }
    __syncthreads();
  }
#pragma unroll
  for (int i = 0; i < 4; ++i) {
    int row = m0 + ty * 4 + i;
    if (row < N_ATOMS) {
#pragma unroll
      for (int j = 0; j < 4; ++j)
        C[row * HIDDEN + n0 + tx * 4 + j] = acc[i][j];
    }
  }
}

// ---------------------------------------------------------------------------
// gather: Hn[a] = relu(base[a] + sum_nb (b!=0 ? Hproj[all_bonds[b][1]] : 0))
// one block (256 threads) per atom.
// ---------------------------------------------------------------------------
__global__ __launch_bounds__(256) void gather_kernel(
    const float* __restrict__ base,
    const float* __restrict__ Hproj,
    const int* __restrict__ aoutgraph,
    const int* __restrict__ all_bonds,
    float* __restrict__ Hn) {
  int a = blockIdx.x;
  int t = threadIdx.x;
  float acc = base[a * HIDDEN + t];
#pragma unroll
  for (int nb = 0; nb < MAX_NB; ++nb) {
    int b = aoutgraph[a * MAX_NB + nb];
    if (b != 0) {
      int s = all_bonds[2 * b + 1];
      acc += Hproj[s * HIDDEN + t];
    }
  }
  Hn[a * HIDDEN + t] = fmaxf(acc, 0.f);
}

// ---------------------------------------------------------------------------
// transpose: out[h][a] = Hn[a][h]   (256 x 100000 output)
// 32x32 LDS tiles, block (32,8).
// ---------------------------------------------------------------------------
__global__ __launch_bounds__(256) void transpose_kernel(
    const float* __restrict__ Hn, float* __restrict__ out) {
  __shared__ float tile[32][33];
  int a0 = blockIdx.x * 32;
  int h0 = blockIdx.y * 32;
  int tx = threadIdx.x, ty = threadIdx.y;
#pragma unroll
  for (int r = 0; r < 4; ++r) {
    int arow = a0 + ty + r * 8;
    float v = 0.f;
    if (arow < N_ATOMS) v = Hn[arow * HIDDEN + h0 + tx];
    tile[ty + r * 8][tx] = v;
  }
  __syncthreads();
#pragma unroll
  for (int r = 0; r < 4; ++r) {
    int hrow = h0 + ty + r * 8;
    int acol = a0 + tx;
    if (acol < N_ATOMS) out[hrow * N_ATOMS + acol] = tile[tx][ty + r * 8];
  }
}

extern "C" void kernel_launch(void* const* d_in, const int* in_sizes, int n_in,
                              void* d_out, int out_size, void* d_ws, size_t ws_size,
                              hipStream_t stream) {
  const float* fatoms = (const float*)d_in[0];
  const float* fbonds = (const float*)d_in[1];
  const int* aoutgraph = (const int*)d_in[2];
  const int* all_bonds = (const int*)d_in[3];
  const float* W_nin = (const float*)d_in[4];
  const float* W_node = (const float*)d_in[5];
  float* out = (float*)d_out;

  const size_t NH = (size_t)N_ATOMS * HIDDEN;
  float* base = (float*)d_ws;        // 102.4 MB
  float* Hn = base + NH;             // 102.4 MB
  float* Hproj = out;                // reuse d_out as scratch during iterations

  init_kernel<<<N_ATOMS, 256, 0, stream>>>(fatoms, fbonds, aoutgraph, W_nin,
                                           W_node, Hn, base);

  dim3 ggrid((N_ATOMS + BM - 1) / BM, HIDDEN / BN);
  for (int it = 0; it < DEPTH; ++it) {
    gemm_kernel<<<ggrid, 256, 0, stream>>>(Hn, W_node, Hproj);
    gather_kernel<<<N_ATOMS, 256, 0, stream>>>(base, Hproj, aoutgraph,
                                               all_bonds, Hn);
  }

  dim3 tgrid((N_ATOMS + 31) / 32, HIDDEN / 32);
  transpose_kernel<<<tgrid, dim3(32, 8), 0, stream>>>(Hn, out);
}

// Round 4
// 1820.460 us; speedup vs baseline: 1.8705x; 1.8705x over previous
//
#include <hip/hip_runtime.h>

#define N_ATOMS 100000
#define N_BONDS 200000
#define MAX_NB 6
#define HIDDEN 256
#define DEPTH 6
#define ATOM_FDIM 39
#define BOND_FDIM 11
#define WNODE_COLS (HIDDEN + BOND_FDIM)  // 267

typedef __attribute__((ext_vector_type(8))) short bf16x8;
typedef __attribute__((ext_vector_type(4))) float f32x4;

__device__ __forceinline__ unsigned short f2bf(float x) {
  unsigned u = __float_as_uint(x);
  unsigned r = (u + 0x7FFFu + ((u >> 16) & 1u)) >> 16;
  return (unsigned short)r;
}
__device__ __forceinline__ float bf2f(unsigned short h) {
  return __uint_as_float(((unsigned)h) << 16);
}
// exact 3-term decomposition: x = t1 + t2 + t3 + O(2^-27 x)
__device__ __forceinline__ void split3(float x, short* s1, short* s2, short* s3) {
  unsigned short h1 = f2bf(x);
  float r1 = x - bf2f(h1);
  unsigned short h2 = f2bf(r1);
  float r2 = r1 - bf2f(h2);
  *s1 = (short)h1;
  *s2 = (short)h2;
  *s3 = (short)f2bf(r2);
}

union U8 { short s[8]; bf16x8 v; };

// ---------------------------------------------------------------------------
// init: per block of 32 atoms (256 thr):
//   Hn = h0 = relu(fatoms @ W_nin.T)   (fp32)
//   base = h0 + (sum_nb fbonds[aoutgraph]) @ W_f.T   (fp32)
// ---------------------------------------------------------------------------
__global__ __launch_bounds__(256) void init_kernel(
    const float* __restrict__ fatoms,
    const float* __restrict__ fbonds,
    const int* __restrict__ aoutgraph,
    const float* __restrict__ W_nin,
    const float* __restrict__ W_node,
    float* __restrict__ Hn,
    float* __restrict__ base) {
  __shared__ float Wn_lds[ATOM_FDIM * 256];   // [k][n]
  __shared__ float Wf_lds[BOND_FDIM * 256];   // [k][n]
  __shared__ float fa_lds[32 * 40];           // [atom][k]
  __shared__ float fs_lds[32 * 12];           // [atom][f]
  int tid = threadIdx.x;
  int a0 = blockIdx.x * 32;

  for (int k = 0; k < ATOM_FDIM; ++k)
    Wn_lds[k * 256 + tid] = W_nin[tid * ATOM_FDIM + k];
  for (int k = 0; k < BOND_FDIM; ++k)
    Wf_lds[k * 256 + tid] = W_node[tid * WNODE_COLS + HIDDEN + k];
  {
    int a_l = tid >> 3, j8 = tid & 7;
#pragma unroll
    for (int jj = 0; jj < 5; ++jj) {
      int k = j8 * 5 + jj;
      if (k < ATOM_FDIM)
        fa_lds[a_l * 40 + k] = fatoms[(size_t)(a0 + a_l) * ATOM_FDIM + k];
    }
  }
  // 384 slots on 256 threads: stride loop (bug fix vs previous round)
  for (int i = tid; i < 384; i += 256) {
    int a_l = i / 12, f = i - a_l * 12;
    if (f < BOND_FDIM) {
      float s = 0.f;
#pragma unroll
      for (int nb = 0; nb < MAX_NB; ++nb) {
        int b = aoutgraph[(size_t)(a0 + a_l) * MAX_NB + nb];
        s += fbonds[(size_t)b * BOND_FDIM + f];
      }
      fs_lds[a_l * 12 + f] = s;
    }
  }
  __syncthreads();

  int l = tid & 63, w = tid >> 6;
  f32x4 acc1[8] = {};
  f32x4 acc2[8] = {};
  for (int k = 0; k < ATOM_FDIM; ++k) {
    f32x4 wv = *(const f32x4*)&Wn_lds[k * 256 + l * 4];
#pragma unroll
    for (int ai = 0; ai < 8; ++ai) {
      float av = fa_lds[(w * 8 + ai) * 40 + k];
      acc1[ai] += wv * av;
    }
  }
  for (int k = 0; k < BOND_FDIM; ++k) {
    f32x4 wv = *(const f32x4*)&Wf_lds[k * 256 + l * 4];
#pragma unroll
    for (int ai = 0; ai < 8; ++ai) {
      float av = fs_lds[(w * 8 + ai) * 12 + k];
      acc2[ai] += wv * av;
    }
  }
#pragma unroll
  for (int ai = 0; ai < 8; ++ai) {
    int a_g = a0 + w * 8 + ai;
    size_t off = (size_t)a_g * HIDDEN + l * 4;
    f32x4 h0v, bs;
#pragma unroll
    for (int j = 0; j < 4; ++j) {
      float h0j = fmaxf(acc1[ai][j], 0.f);
      h0v[j] = h0j;
      bs[j] = h0j + acc2[ai][j];
    }
    *(f32x4*)&Hn[off] = h0v;
    *(f32x4*)&base[off] = bs;
  }
}

// ---------------------------------------------------------------------------
// fused iteration: Hn_out = relu(base + (sum_nb [b!=0] Hn_in[src]) @ W_h.T)
// block = 64 atoms x 256 cols; 256 thr (4 waves, wave = 64 atoms x 64 cols).
// Gather-sum in registers (fp32) -> 3-term bf16 split in LDS -> 6-product MFMA.
// ---------------------------------------------------------------------------
#define KCH 32
#define AST 40  // LDS row stride in bf16 (32 + 8 pad; 80 B, 16B-aligned)

__global__ __launch_bounds__(256, 2) void fused_kernel(
    const float* __restrict__ Hn_in,
    const float* __restrict__ base,
    const float* __restrict__ W,          // W_node [256][267]
    const int* __restrict__ aout,
    const int* __restrict__ bonds,
    float* __restrict__ Hn_out) {
  __shared__ short As[3][64 * AST];       // 15.4 KB
  __shared__ short Bs[3][256 * AST];      // 61.4 KB
  __shared__ int src_lds[384];
  int tid = threadIdx.x;
  int a0 = blockIdx.x * 64;

  // 384 slots on 256 threads: stride loop (bug fix vs previous round)
  for (int i = tid; i < 384; i += 256) {
    int a_l = i / 6, nb = i - a_l * 6;
    int a = a0 + a_l;
    int s = -1;
    if (a < N_ATOMS) {
      int b = aout[(size_t)a * MAX_NB + nb];
      if (b != 0) s = bonds[2 * b + 1];
    }
    src_lds[i] = s;
  }
  __syncthreads();

  int lane = tid & 63, w = tid >> 6;
  int lr = lane & 15, lk = lane >> 4;
  int r_a = tid >> 2, q_a = tid & 3;      // A-staging: row, k-quad
  const int* sp = &src_lds[r_a * 6];
  f32x4 acc[4][4] = {};

  for (int k0 = 0; k0 < HIDDEN; k0 += KCH) {
    // ---- stage A: gather-sum 8 fp32 per thread, split to 3 bf16 terms ----
    {
      f32x4 vlo = {0.f, 0.f, 0.f, 0.f}, vhi = {0.f, 0.f, 0.f, 0.f};
#pragma unroll
      for (int nb = 0; nb < MAX_NB; ++nb) {
        int s = sp[nb];
        if (s >= 0) {
          const float* hp = &Hn_in[(size_t)s * HIDDEN + k0 + q_a * 8];
          vlo += *(const f32x4*)hp;
          vhi += *(const f32x4*)(hp + 4);
        }
      }
      U8 t1, t2, t3;
#pragma unroll
      for (int j = 0; j < 4; ++j) split3(vlo[j], &t1.s[j], &t2.s[j], &t3.s[j]);
#pragma unroll
      for (int j = 0; j < 4; ++j)
        split3(vhi[j], &t1.s[4 + j], &t2.s[4 + j], &t3.s[4 + j]);
      int ao = r_a * AST + q_a * 8;
      *(bf16x8*)&As[0][ao] = t1.v;
      *(bf16x8*)&As[1][ao] = t2.v;
      *(bf16x8*)&As[2][ao] = t3.v;
    }
    // ---- stage B: split W chunk (vectorizable consecutive loads) ----
#pragma unroll
    for (int j4 = 0; j4 < 4; ++j4) {
      int f = tid + j4 * 256;
      int n = f >> 2, q = f & 3;
      const float* wp = &W[(size_t)n * WNODE_COLS + k0 + q * 8];
      U8 u1, u2, u3;
#pragma unroll
      for (int j = 0; j < 8; ++j) split3(wp[j], &u1.s[j], &u2.s[j], &u3.s[j]);
      int bo = n * AST + q * 8;
      *(bf16x8*)&Bs[0][bo] = u1.v;
      *(bf16x8*)&Bs[1][bo] = u2.v;
      *(bf16x8*)&Bs[2][bo] = u3.v;
    }
    __syncthreads();

    // ---- MFMA: 6 products per (m,n) ----
    bf16x8 af0[4], af1[4], af2[4], bf0[4], bf1[4], bf2[4];
#pragma unroll
    for (int m = 0; m < 4; ++m) {
      int ao = (m * 16 + lr) * AST + lk * 8;
      af0[m] = *(const bf16x8*)&As[0][ao];
      af1[m] = *(const bf16x8*)&As[1][ao];
      af2[m] = *(const bf16x8*)&As[2][ao];
    }
#pragma unroll
    for (int n = 0; n < 4; ++n) {
      int bo = (w * 64 + n * 16 + lr) * AST + lk * 8;
      bf0[n] = *(const bf16x8*)&Bs[0][bo];
      bf1[n] = *(const bf16x8*)&Bs[1][bo];
      bf2[n] = *(const bf16x8*)&Bs[2][bo];
    }
#pragma unroll
    for (int m = 0; m < 4; ++m)
#pragma unroll
      for (int n = 0; n < 4; ++n) {
        f32x4 c = acc[m][n];
        c = __builtin_amdgcn_mfma_f32_16x16x32_bf16(af0[m], bf0[n], c, 0, 0, 0);
        c = __builtin_amdgcn_mfma_f32_16x16x32_bf16(af0[m], bf1[n], c, 0, 0, 0);
        c = __builtin_amdgcn_mfma_f32_16x16x32_bf16(af1[m], bf0[n], c, 0, 0, 0);
        c = __builtin_amdgcn_mfma_f32_16x16x32_bf16(af1[m], bf1[n], c, 0, 0, 0);
        c = __builtin_amdgcn_mfma_f32_16x16x32_bf16(af0[m], bf2[n], c, 0, 0, 0);
        c = __builtin_amdgcn_mfma_f32_16x16x32_bf16(af2[m], bf0[n], c, 0, 0, 0);
        acc[m][n] = c;
      }
    __syncthreads();
  }

  // ---- epilogue: relu(base + acc) -> Hn_out ----
#pragma unroll
  for (int m = 0; m < 4; ++m) {
    int row0 = a0 + m * 16 + lk * 4;
#pragma unroll
    for (int n = 0; n < 4; ++n) {
      int col = w * 64 + n * 16 + lr;
#pragma unroll
      for (int r = 0; r < 4; ++r) {
        int row = row0 + r;
        if (row < N_ATOMS) {
          size_t off = (size_t)row * HIDDEN + col;
          Hn_out[off] = fmaxf(base[off] + acc[m][n][r], 0.f);
        }
      }
    }
  }
}

// ---------------------------------------------------------------------------
// transpose: out[h][a] = Hn[a][h]; 64x64 tiles.
// ---------------------------------------------------------------------------
__global__ __launch_bounds__(256) void transpose_kernel(
    const float* __restrict__ Hn, float* __restrict__ out) {
  __shared__ float tile[64][68];
  int a0 = blockIdx.x * 64, h0 = blockIdx.y * 64;
  int tid = threadIdx.x;
#pragma unroll
  for (int p = 0; p < 2; ++p) {
    int id = tid + p * 256;
    int r = id >> 3, c8 = (id & 7) * 8;
    int ag = a0 + r;
    if (ag > N_ATOMS - 1) ag = N_ATOMS - 1;
    const float* hp = &Hn[(size_t)ag * HIDDEN + h0 + c8];
    *(f32x4*)&tile[r][c8] = *(const f32x4*)hp;
    *(f32x4*)&tile[r][c8 + 4] = *(const f32x4*)(hp + 4);
  }
  __syncthreads();
  int h = tid >> 2, as = (tid & 3) * 16;
  size_t ob = (size_t)(h0 + h) * N_ATOMS + a0 + as;
  if (a0 + 64 <= N_ATOMS) {
#pragma unroll
    for (int q = 0; q < 4; ++q) {
      f32x4 v;
#pragma unroll
      for (int j = 0; j < 4; ++j) v[j] = tile[as + q * 4 + j][h];
      *(f32x4*)&out[ob + q * 4] = v;
    }
  } else {
    for (int j = 0; j < 16; ++j)
      if (a0 + as + j < N_ATOMS) out[ob + j] = tile[as + j][h];
  }
}

extern "C" void kernel_launch(void* const* d_in, const int* in_sizes, int n_in,
                              void* d_out, int out_size, void* d_ws, size_t ws_size,
                              hipStream_t stream) {
  const float* fatoms = (const float*)d_in[0];
  const float* fbonds = (const float*)d_in[1];
  const int* aoutgraph = (const int*)d_in[2];
  const int* all_bonds = (const int*)d_in[3];
  const float* W_nin = (const float*)d_in[4];
  const float* W_node = (const float*)d_in[5];
  float* out = (float*)d_out;

  const size_t NH = (size_t)N_ATOMS * HIDDEN;
  float* base = (float*)d_ws;        // 102.4 MB
  float* HnA = base + NH;            // 102.4 MB (total ws use = 204.8 MB, proven)
  float* HnB = out;                  // d_out doubles as ping-pong buffer

  init_kernel<<<N_ATOMS / 32, 256, 0, stream>>>(fatoms, fbonds, aoutgraph,
                                                W_nin, W_node, HnA, base);

  const int nblk = (N_ATOMS + 63) / 64;  // 1563
  for (int it = 0; it < DEPTH; ++it) {
    const float* in = (it & 1) ? HnB : HnA;
    float* o = (it & 1) ? HnA : HnB;
    fused_kernel<<<nblk, 256, 0, stream>>>(in, base, W_node, aoutgraph,
                                           all_bonds, o);
  }
  // DEPTH even -> final Hn is in HnA; d_out is free to receive the transpose.
  dim3 tgrid(nblk, HIDDEN / 64);
  transpose_kernel<<<tgrid, 256, 0, stream>>>(HnA, out);
}

// Round 5
// 1633.688 us; speedup vs baseline: 2.0843x; 1.1143x over previous
//
#include <hip/hip_runtime.h>

#define N_ATOMS 100000
#define N_BONDS 200000
#define MAX_NB 6
#define HIDDEN 256
#define DEPTH 6
#define ATOM_FDIM 39
#define BOND_FDIM 11
#define WNODE_COLS (HIDDEN + BOND_FDIM)  // 267

typedef __attribute__((ext_vector_type(8))) short bf16x8;
typedef __attribute__((ext_vector_type(4))) float f32x4;

__device__ __forceinline__ unsigned short f2bf(float x) {
  unsigned u = __float_as_uint(x);
  unsigned r = (u + 0x7FFFu + ((u >> 16) & 1u)) >> 16;
  return (unsigned short)r;
}
__device__ __forceinline__ float bf2f(unsigned short h) {
  return __uint_as_float(((unsigned)h) << 16);
}
// exact 3-term decomposition: x = t1 + t2 + t3 + O(2^-27 x)
__device__ __forceinline__ void split3(float x, short* s1, short* s2, short* s3) {
  unsigned short h1 = f2bf(x);
  float r1 = x - bf2f(h1);
  unsigned short h2 = f2bf(r1);
  float r2 = r1 - bf2f(h2);
  *s1 = (short)h1;
  *s2 = (short)h2;
  *s3 = (short)f2bf(r2);
}

union U8 { short s[8]; bf16x8 v; };

// ---------------------------------------------------------------------------
// split_w: one-off. Bsp[t][n][k] = term t of split3(W_node[n][k]), k<256.
// 64 blocks x 256 thr; each thread splits 4 consecutive k of one n-row.
// ---------------------------------------------------------------------------
__global__ __launch_bounds__(256) void split_w_kernel(
    const float* __restrict__ W, short* __restrict__ Bsp) {
  int g = blockIdx.x * 256 + threadIdx.x;  // 16384
  int n = g >> 6;
  int k4 = (g & 63) * 4;
  const float* wp = &W[(size_t)n * WNODE_COLS + k4];
  int o = n * 256 + k4;
#pragma unroll
  for (int j = 0; j < 4; ++j) {
    short a, b, c;
    split3(wp[j], &a, &b, &c);
    Bsp[o + j] = a;
    Bsp[65536 + o + j] = b;
    Bsp[131072 + o + j] = c;
  }
}

// ---------------------------------------------------------------------------
// init: per block of 32 atoms (256 thr):
//   Hn = h0 = relu(fatoms @ W_nin.T)   (fp32)
//   base = h0 + (sum_nb fbonds[aoutgraph]) @ W_f.T   (fp32)
// ---------------------------------------------------------------------------
__global__ __launch_bounds__(256) void init_kernel(
    const float* __restrict__ fatoms,
    const float* __restrict__ fbonds,
    const int* __restrict__ aoutgraph,
    const float* __restrict__ W_nin,
    const float* __restrict__ W_node,
    float* __restrict__ Hn,
    float* __restrict__ base) {
  __shared__ float Wn_lds[ATOM_FDIM * 256];   // [k][n]
  __shared__ float Wf_lds[BOND_FDIM * 256];   // [k][n]
  __shared__ float fa_lds[32 * 40];           // [atom][k]
  __shared__ float fs_lds[32 * 12];           // [atom][f]
  int tid = threadIdx.x;
  int a0 = blockIdx.x * 32;

  for (int k = 0; k < ATOM_FDIM; ++k)
    Wn_lds[k * 256 + tid] = W_nin[tid * ATOM_FDIM + k];
  for (int k = 0; k < BOND_FDIM; ++k)
    Wf_lds[k * 256 + tid] = W_node[tid * WNODE_COLS + HIDDEN + k];
  {
    int a_l = tid >> 3, j8 = tid & 7;
#pragma unroll
    for (int jj = 0; jj < 5; ++jj) {
      int k = j8 * 5 + jj;
      if (k < ATOM_FDIM)
        fa_lds[a_l * 40 + k] = fatoms[(size_t)(a0 + a_l) * ATOM_FDIM + k];
    }
  }
  for (int i = tid; i < 384; i += 256) {
    int a_l = i / 12, f = i - a_l * 12;
    if (f < BOND_FDIM) {
      float s = 0.f;
#pragma unroll
      for (int nb = 0; nb < MAX_NB; ++nb) {
        int b = aoutgraph[(size_t)(a0 + a_l) * MAX_NB + nb];
        s += fbonds[(size_t)b * BOND_FDIM + f];
      }
      fs_lds[a_l * 12 + f] = s;
    }
  }
  __syncthreads();

  int l = tid & 63, w = tid >> 6;
  f32x4 acc1[8] = {};
  f32x4 acc2[8] = {};
  for (int k = 0; k < ATOM_FDIM; ++k) {
    f32x4 wv = *(const f32x4*)&Wn_lds[k * 256 + l * 4];
#pragma unroll
    for (int ai = 0; ai < 8; ++ai) {
      float av = fa_lds[(w * 8 + ai) * 40 + k];
      acc1[ai] += wv * av;
    }
  }
  for (int k = 0; k < BOND_FDIM; ++k) {
    f32x4 wv = *(const f32x4*)&Wf_lds[k * 256 + l * 4];
#pragma unroll
    for (int ai = 0; ai < 8; ++ai) {
      float av = fs_lds[(w * 8 + ai) * 12 + k];
      acc2[ai] += wv * av;
    }
  }
#pragma unroll
  for (int ai = 0; ai < 8; ++ai) {
    int a_g = a0 + w * 8 + ai;
    size_t off = (size_t)a_g * HIDDEN + l * 4;
    f32x4 h0v, bs;
#pragma unroll
    for (int j = 0; j < 4; ++j) {
      float h0j = fmaxf(acc1[ai][j], 0.f);
      h0v[j] = h0j;
      bs[j] = h0j + acc2[ai][j];
    }
    *(f32x4*)&Hn[off] = h0v;
    *(f32x4*)&base[off] = bs;
  }
}

// ---------------------------------------------------------------------------
// fused iteration: Hn_out = relu(base + (sum_nb [b!=0] Hn_in[src]) @ W_h.T)
// block = 64 atoms x 256 cols; 256 thr (4 waves; wave w owns cols w*64..+63).
// A: gather-sum fp32 -> split3 -> double-buffered LDS (1 barrier/chunk).
// B: pre-split bf16 terms loaded straight from L2 (no LDS, no per-block split).
// ---------------------------------------------------------------------------
#define KCH 32
#define AST 40  // LDS row stride in bf16 (32 + 8 pad; 80 B, 16B-aligned)

__global__ __launch_bounds__(256, 3) void fused_kernel(
    const float* __restrict__ Hn_in,
    const float* __restrict__ base,
    const short* __restrict__ Bsp,        // [3][256][256] bf16 terms
    const int* __restrict__ aout,
    const int* __restrict__ bonds,
    float* __restrict__ Hn_out) {
  __shared__ short As[2][3][64 * AST];    // 30.7 KB
  __shared__ int src_lds[384];
  int tid = threadIdx.x;
  int a0 = blockIdx.x * 64;

  for (int i = tid; i < 384; i += 256) {
    int a_l = i / 6, nb = i - a_l * 6;
    int a = a0 + a_l;
    int s = -1;
    if (a < N_ATOMS) {
      int b = aout[(size_t)a * MAX_NB + nb];
      if (b != 0) s = bonds[2 * b + 1];
    }
    src_lds[i] = s;
  }
  __syncthreads();

  int lane = tid & 63, w = tid >> 6;
  int lr = lane & 15, lk = lane >> 4;
  int r_a = tid >> 2, q_a = tid & 3;      // staging role: row, k-oct
  const int* sp = &src_lds[r_a * 6];
  f32x4 acc[4][4] = {};

  // ---- stage chunk 0 into buffer 0 ----
  {
    f32x4 vlo = {0.f, 0.f, 0.f, 0.f}, vhi = {0.f, 0.f, 0.f, 0.f};
#pragma unroll
    for (int nb = 0; nb < MAX_NB; ++nb) {
      int s = sp[nb];
      int sr = s >= 0 ? s : 0;
      float wt = s >= 0 ? 1.f : 0.f;
      const float* hp = &Hn_in[(size_t)sr * HIDDEN + q_a * 8];
      f32x4 va = *(const f32x4*)hp;
      f32x4 vb = *(const f32x4*)(hp + 4);
      vlo += va * wt;
      vhi += vb * wt;
    }
    U8 t1, t2, t3;
#pragma unroll
    for (int j = 0; j < 4; ++j) split3(vlo[j], &t1.s[j], &t2.s[j], &t3.s[j]);
#pragma unroll
    for (int j = 0; j < 4; ++j)
      split3(vhi[j], &t1.s[4 + j], &t2.s[4 + j], &t3.s[4 + j]);
    int ao = r_a * AST + q_a * 8;
    *(bf16x8*)&As[0][0][ao] = t1.v;
    *(bf16x8*)&As[0][1][ao] = t2.v;
    *(bf16x8*)&As[0][2][ao] = t3.v;
  }
  __syncthreads();

  int p = 0;
  for (int c = 0; c < 8; ++c) {
    int k0 = c * KCH;
    // ---- B fragments straight from L2 (pre-split) ----
    bf16x8 bf0[4], bf1[4], bf2[4];
#pragma unroll
    for (int n = 0; n < 4; ++n) {
      int bo = (w * 64 + n * 16 + lr) * 256 + k0 + lk * 8;
      bf0[n] = *(const bf16x8*)&Bsp[bo];
      bf1[n] = *(const bf16x8*)&Bsp[65536 + bo];
      bf2[n] = *(const bf16x8*)&Bsp[131072 + bo];
    }
    // ---- stage chunk c+1 into As[p^1] (no race: others read As[p]) ----
    if (c < 7) {
      int k1 = k0 + KCH;
      f32x4 vlo = {0.f, 0.f, 0.f, 0.f}, vhi = {0.f, 0.f, 0.f, 0.f};
#pragma unroll
      for (int nb = 0; nb < MAX_NB; ++nb) {
        int s = sp[nb];
        int sr = s >= 0 ? s : 0;
        float wt = s >= 0 ? 1.f : 0.f;
        const float* hp = &Hn_in[(size_t)sr * HIDDEN + k1 + q_a * 8];
        f32x4 va = *(const f32x4*)hp;
        f32x4 vb = *(const f32x4*)(hp + 4);
        vlo += va * wt;
        vhi += vb * wt;
      }
      U8 t1, t2, t3;
#pragma unroll
      for (int j = 0; j < 4; ++j) split3(vlo[j], &t1.s[j], &t2.s[j], &t3.s[j]);
#pragma unroll
      for (int j = 0; j < 4; ++j)
        split3(vhi[j], &t1.s[4 + j], &t2.s[4 + j], &t3.s[4 + j]);
      int ao = r_a * AST + q_a * 8;
      *(bf16x8*)&As[p ^ 1][0][ao] = t1.v;
      *(bf16x8*)&As[p ^ 1][1][ao] = t2.v;
      *(bf16x8*)&As[p ^ 1][2][ao] = t3.v;
    }
    // ---- MFMA: 6 products per (m,n) ----
#pragma unroll
    for (int m = 0; m < 4; ++m) {
      int ao = (m * 16 + lr) * AST + lk * 8;
      bf16x8 af0 = *(const bf16x8*)&As[p][0][ao];
      bf16x8 af1 = *(const bf16x8*)&As[p][1][ao];
      bf16x8 af2 = *(const bf16x8*)&As[p][2][ao];
#pragma unroll
      for (int n = 0; n < 4; ++n) {
        f32x4 cc = acc[m][n];
        cc = __builtin_amdgcn_mfma_f32_16x16x32_bf16(af0, bf0[n], cc, 0, 0, 0);
        cc = __builtin_amdgcn_mfma_f32_16x16x32_bf16(af0, bf1[n], cc, 0, 0, 0);
        cc = __builtin_amdgcn_mfma_f32_16x16x32_bf16(af1, bf0[n], cc, 0, 0, 0);
        cc = __builtin_amdgcn_mfma_f32_16x16x32_bf16(af1, bf1[n], cc, 0, 0, 0);
        cc = __builtin_amdgcn_mfma_f32_16x16x32_bf16(af0, bf2[n], cc, 0, 0, 0);
        cc = __builtin_amdgcn_mfma_f32_16x16x32_bf16(af2, bf0[n], cc, 0, 0, 0);
        acc[m][n] = cc;
      }
    }
    __syncthreads();
    p ^= 1;
  }

  // ---- epilogue: relu(base + acc) -> Hn_out ----
#pragma unroll
  for (int m = 0; m < 4; ++m) {
    int row0 = a0 + m * 16 + lk * 4;
#pragma unroll
    for (int n = 0; n < 4; ++n) {
      int col = w * 64 + n * 16 + lr;
#pragma unroll
      for (int r = 0; r < 4; ++r) {
        int row = row0 + r;
        if (row < N_ATOMS) {
          size_t off = (size_t)row * HIDDEN + col;
          Hn_out[off] = fmaxf(base[off] + acc[m][n][r], 0.f);
        }
      }
    }
  }
}

// ---------------------------------------------------------------------------
// transpose: out[h][a] = Hn[a][h]; 64x64 tiles.
// ---------------------------------------------------------------------------
__global__ __launch_bounds__(256) void transpose_kernel(
    const float* __restrict__ Hn, float* __restrict__ out) {
  __shared__ float tile[64][68];
  int a0 = blockIdx.x * 64, h0 = blockIdx.y * 64;
  int tid = threadIdx.x;
#pragma unroll
  for (int p = 0; p < 2; ++p) {
    int id = tid + p * 256;
    int r = id >> 3, c8 = (id & 7) * 8;
    int ag = a0 + r;
    if (ag > N_ATOMS - 1) ag = N_ATOMS - 1;
    const float* hp = &Hn[(size_t)ag * HIDDEN + h0 + c8];
    *(f32x4*)&tile[r][c8] = *(const f32x4*)hp;
    *(f32x4*)&tile[r][c8 + 4] = *(const f32x4*)(hp + 4);
  }
  __syncthreads();
  int h = tid >> 2, as = (tid & 3) * 16;
  size_t ob = (size_t)(h0 + h) * N_ATOMS + a0 + as;
  if (a0 + 64 <= N_ATOMS) {
#pragma unroll
    for (int q = 0; q < 4; ++q) {
      f32x4 v;
#pragma unroll
      for (int j = 0; j < 4; ++j) v[j] = tile[as + q * 4 + j][h];
      *(f32x4*)&out[ob + q * 4] = v;
    }
  } else {
    for (int j = 0; j < 16; ++j)
      if (a0 + as + j < N_ATOMS) out[ob + j] = tile[as + j][h];
  }
}

extern "C" void kernel_launch(void* const* d_in, const int* in_sizes, int n_in,
                              void* d_out, int out_size, void* d_ws, size_t ws_size,
                              hipStream_t stream) {
  const float* fatoms = (const float*)d_in[0];
  const float* fbonds = (const float*)d_in[1];
  const int* aoutgraph = (const int*)d_in[2];
  const int* all_bonds = (const int*)d_in[3];
  const float* W_nin = (const float*)d_in[4];
  const float* W_node = (const float*)d_in[5];
  float* out = (float*)d_out;

  const size_t NH = (size_t)N_ATOMS * HIDDEN;
  float* base = (float*)d_ws;        // 102.4 MB
  float* HnA = base + NH;            // 102.4 MB
  short* Bsp = (short*)(HnA + NH);   // 384 KB pre-split W terms
  float* HnB = out;                  // d_out doubles as ping-pong buffer

  split_w_kernel<<<64, 256, 0, stream>>>(W_node, Bsp);
  init_kernel<<<N_ATOMS / 32, 256, 0, stream>>>(fatoms, fbonds, aoutgraph,
                                                W_nin, W_node, HnA, base);

  const int nblk = (N_ATOMS + 63) / 64;  // 1563
  for (int it = 0; it < DEPTH; ++it) {
    const float* in = (it & 1) ? HnB : HnA;
    float* o = (it & 1) ? HnA : HnB;
    fused_kernel<<<nblk, 256, 0, stream>>>(in, base, Bsp, aoutgraph,
                                           all_bonds, o);
  }
  // DEPTH even -> final Hn is in HnA; d_out receives the transpose.
  dim3 tgrid(nblk, HIDDEN / 64);
  transpose_kernel<<<tgrid, 256, 0, stream>>>(HnA, out);
}

// Round 6
// 1555.645 us; speedup vs baseline: 2.1889x; 1.0502x over previous
//
#include <hip/hip_runtime.h>

#define N_ATOMS 100000
#define N_BONDS 200000
#define MAX_NB 6
#define HIDDEN 256
#define DEPTH 6
#define ATOM_FDIM 39
#define BOND_FDIM 11
#define WNODE_COLS (HIDDEN + BOND_FDIM)  // 267

typedef __attribute__((ext_vector_type(8))) short bf16x8;
typedef __attribute__((ext_vector_type(4))) float f32x4;

__device__ __forceinline__ unsigned short f2bf(float x) {
  unsigned u = __float_as_uint(x);
  unsigned r = (u + 0x7FFFu + ((u >> 16) & 1u)) >> 16;
  return (unsigned short)r;
}
__device__ __forceinline__ float bf2f(unsigned short h) {
  return __uint_as_float(((unsigned)h) << 16);
}
// exact 3-term decomposition: x = t1 + t2 + t3 + O(2^-27 x)
__device__ __forceinline__ void split3(float x, short* s1, short* s2, short* s3) {
  unsigned short h1 = f2bf(x);
  float r1 = x - bf2f(h1);
  unsigned short h2 = f2bf(r1);
  float r2 = r1 - bf2f(h2);
  *s1 = (short)h1;
  *s2 = (short)h2;
  *s3 = (short)f2bf(r2);
}

union U8 { short s[8]; bf16x8 v; };

// ---------------------------------------------------------------------------
// split_w: one-off. Bsp[t][n][k] = term t of split3(W_node[n][k]), k<256.
// ---------------------------------------------------------------------------
__global__ __launch_bounds__(256) void split_w_kernel(
    const float* __restrict__ W, short* __restrict__ Bsp) {
  int g = blockIdx.x * 256 + threadIdx.x;  // 16384
  int n = g >> 6;
  int k4 = (g & 63) * 4;
  const float* wp = &W[(size_t)n * WNODE_COLS + k4];
  int o = n * 256 + k4;
#pragma unroll
  for (int j = 0; j < 4; ++j) {
    short a, b, c;
    split3(wp[j], &a, &b, &c);
    Bsp[o + j] = a;
    Bsp[65536 + o + j] = b;
    Bsp[131072 + o + j] = c;
  }
}

// ---------------------------------------------------------------------------
// init: per block of 32 atoms (256 thr):
//   Hn = h0 = relu(fatoms @ W_nin.T)   (fp32)
//   base = h0 + (sum_nb fbonds[aoutgraph]) @ W_f.T   (fp32)
// ---------------------------------------------------------------------------
__global__ __launch_bounds__(256) void init_kernel(
    const float* __restrict__ fatoms,
    const float* __restrict__ fbonds,
    const int* __restrict__ aoutgraph,
    const float* __restrict__ W_nin,
    const float* __restrict__ W_node,
    float* __restrict__ Hn,
    float* __restrict__ base) {
  __shared__ float Wn_lds[ATOM_FDIM * 256];   // [k][n]
  __shared__ float Wf_lds[BOND_FDIM * 256];   // [k][n]
  __shared__ float fa_lds[32 * 40];           // [atom][k]
  __shared__ float fs_lds[32 * 12];           // [atom][f]
  int tid = threadIdx.x;
  int a0 = blockIdx.x * 32;

  for (int k = 0; k < ATOM_FDIM; ++k)
    Wn_lds[k * 256 + tid] = W_nin[tid * ATOM_FDIM + k];
  for (int k = 0; k < BOND_FDIM; ++k)
    Wf_lds[k * 256 + tid] = W_node[tid * WNODE_COLS + HIDDEN + k];
  {
    int a_l = tid >> 3, j8 = tid & 7;
#pragma unroll
    for (int jj = 0; jj < 5; ++jj) {
      int k = j8 * 5 + jj;
      if (k < ATOM_FDIM)
        fa_lds[a_l * 40 + k] = fatoms[(size_t)(a0 + a_l) * ATOM_FDIM + k];
    }
  }
  for (int i = tid; i < 384; i += 256) {
    int a_l = i / 12, f = i - a_l * 12;
    if (f < BOND_FDIM) {
      float s = 0.f;
#pragma unroll
      for (int nb = 0; nb < MAX_NB; ++nb) {
        int b = aoutgraph[(size_t)(a0 + a_l) * MAX_NB + nb];
        s += fbonds[(size_t)b * BOND_FDIM + f];
      }
      fs_lds[a_l * 12 + f] = s;
    }
  }
  __syncthreads();

  int l = tid & 63, w = tid >> 6;
  f32x4 acc1[8] = {};
  f32x4 acc2[8] = {};
  for (int k = 0; k < ATOM_FDIM; ++k) {
    f32x4 wv = *(const f32x4*)&Wn_lds[k * 256 + l * 4];
#pragma unroll
    for (int ai = 0; ai < 8; ++ai) {
      float av = fa_lds[(w * 8 + ai) * 40 + k];
      acc1[ai] += wv * av;
    }
  }
  for (int k = 0; k < BOND_FDIM; ++k) {
    f32x4 wv = *(const f32x4*)&Wf_lds[k * 256 + l * 4];
#pragma unroll
    for (int ai = 0; ai < 8; ++ai) {
      float av = fs_lds[(w * 8 + ai) * 12 + k];
      acc2[ai] += wv * av;
    }
  }
#pragma unroll
  for (int ai = 0; ai < 8; ++ai) {
    int a_g = a0 + w * 8 + ai;
    size_t off = (size_t)a_g * HIDDEN + l * 4;
    f32x4 h0v, bs;
#pragma unroll
    for (int j = 0; j < 4; ++j) {
      float h0j = fmaxf(acc1[ai][j], 0.f);
      h0v[j] = h0j;
      bs[j] = h0j + acc2[ai][j];
    }
    *(f32x4*)&Hn[off] = h0v;
    *(f32x4*)&base[off] = bs;
  }
}

// ---------------------------------------------------------------------------
// fused iteration: Hn_out = relu(base + (sum_nb [b!=0] Hn_in[src]) @ W_h.T)
// block = 64 atoms x 256 cols; 256 thr (4 waves; wave w owns cols w*64..+63).
// Chunk pipeline (fully unrolled, 1 barrier/chunk):
//   issue gather loads (c+1) -> MFMA(c) [setprio] -> split3+ds_write (c+1)
// B pre-split bf16 from L2; Hn_out written with NT stores (keep L3 for
// Hn_in + base residency).
// ---------------------------------------------------------------------------
#define KCH 32
#define AST 40  // LDS row stride in bf16 (32 + 8 pad; 80 B, 16B-aligned)

__global__ __launch_bounds__(256) void fused_kernel(
    const float* __restrict__ Hn_in,
    const float* __restrict__ base,
    const short* __restrict__ Bsp,        // [3][256][256] bf16 terms
    const int* __restrict__ aout,
    const int* __restrict__ bonds,
    float* __restrict__ Hn_out) {
  __shared__ short As[2][3][64 * AST];    // 30.7 KB
  __shared__ int src_lds[384];
  int tid = threadIdx.x;
  int a0 = blockIdx.x * 64;

  for (int i = tid; i < 384; i += 256) {
    int a_l = i / 6, nb = i - a_l * 6;
    int a = a0 + a_l;
    int s = -1;
    if (a < N_ATOMS) {
      int b = aout[(size_t)a * MAX_NB + nb];
      if (b != 0) s = bonds[2 * b + 1];
    }
    src_lds[i] = s;
  }
  __syncthreads();

  int lane = tid & 63, w = tid >> 6;
  int lr = lane & 15, lk = lane >> 4;
  int r_a = tid >> 2, q_a = tid & 3;      // staging role: row, k-oct

  // hoist per-thread gather sources into registers
  const float* gp[MAX_NB];
  float gw[MAX_NB];
#pragma unroll
  for (int nb = 0; nb < MAX_NB; ++nb) {
    int s = src_lds[r_a * 6 + nb];
    int sr = s >= 0 ? s : 0;
    gw[nb] = s >= 0 ? 1.f : 0.f;
    gp[nb] = &Hn_in[(size_t)sr * HIDDEN + q_a * 8];
  }
  int ao_st = r_a * AST + q_a * 8;        // LDS write slot

  f32x4 acc[4][4] = {};

  // ---- prologue: gather+split chunk 0 into As[0] ----
  {
    f32x4 vlo = {0.f, 0.f, 0.f, 0.f}, vhi = {0.f, 0.f, 0.f, 0.f};
#pragma unroll
    for (int nb = 0; nb < MAX_NB; ++nb) {
      vlo += *(const f32x4*)(gp[nb]) * gw[nb];
      vhi += *(const f32x4*)(gp[nb] + 4) * gw[nb];
    }
    U8 t1, t2, t3;
#pragma unroll
    for (int j = 0; j < 4; ++j) split3(vlo[j], &t1.s[j], &t2.s[j], &t3.s[j]);
#pragma unroll
    for (int j = 0; j < 4; ++j)
      split3(vhi[j], &t1.s[4 + j], &t2.s[4 + j], &t3.s[4 + j]);
    *(bf16x8*)&As[0][0][ao_st] = t1.v;
    *(bf16x8*)&As[0][1][ao_st] = t2.v;
    *(bf16x8*)&As[0][2][ao_st] = t3.v;
  }
  __syncthreads();

#pragma unroll
  for (int c = 0; c < 8; ++c) {
    const int cur = c & 1;
    // ---- issue gather loads for chunk c+1 (kept in regs across MFMA) ----
    f32x4 ga[MAX_NB], gb[MAX_NB];
    if (c < 7) {
      const int k1 = (c + 1) * KCH;
#pragma unroll
      for (int nb = 0; nb < MAX_NB; ++nb) {
        ga[nb] = *(const f32x4*)(gp[nb] + k1);
        gb[nb] = *(const f32x4*)(gp[nb] + k1 + 4);
      }
    }
    // ---- A fragments from LDS ----
    bf16x8 af0[4], af1[4], af2[4];
#pragma unroll
    for (int m = 0; m < 4; ++m) {
      int ao = (m * 16 + lr) * AST + lk * 8;
      af0[m] = *(const bf16x8*)&As[cur][0][ao];
      af1[m] = *(const bf16x8*)&As[cur][1][ao];
      af2[m] = *(const bf16x8*)&As[cur][2][ao];
    }
    // ---- MFMA cluster: 6 products per (m,n) ----
    __builtin_amdgcn_s_setprio(1);
#pragma unroll
    for (int n = 0; n < 4; ++n) {
      int bo = (w * 64 + n * 16 + lr) * 256 + c * KCH + lk * 8;
      bf16x8 b0 = *(const bf16x8*)&Bsp[bo];
      bf16x8 b1 = *(const bf16x8*)&Bsp[65536 + bo];
      bf16x8 b2 = *(const bf16x8*)&Bsp[131072 + bo];
#pragma unroll
      for (int m = 0; m < 4; ++m) {
        f32x4 cc = acc[m][n];
        cc = __builtin_amdgcn_mfma_f32_16x16x32_bf16(af0[m], b0, cc, 0, 0, 0);
        cc = __builtin_amdgcn_mfma_f32_16x16x32_bf16(af0[m], b1, cc, 0, 0, 0);
        cc = __builtin_amdgcn_mfma_f32_16x16x32_bf16(af1[m], b0, cc, 0, 0, 0);
        cc = __builtin_amdgcn_mfma_f32_16x16x32_bf16(af1[m], b1, cc, 0, 0, 0);
        cc = __builtin_amdgcn_mfma_f32_16x16x32_bf16(af0[m], b2, cc, 0, 0, 0);
        cc = __builtin_amdgcn_mfma_f32_16x16x32_bf16(af2[m], b0, cc, 0, 0, 0);
        acc[m][n] = cc;
      }
    }
    __builtin_amdgcn_s_setprio(0);
    // ---- finish gather c+1: sum, split, LDS write ----
    if (c < 7) {
      f32x4 vlo = {0.f, 0.f, 0.f, 0.f}, vhi = {0.f, 0.f, 0.f, 0.f};
#pragma unroll
      for (int nb = 0; nb < MAX_NB; ++nb) {
        vlo += ga[nb] * gw[nb];
        vhi += gb[nb] * gw[nb];
      }
      U8 t1, t2, t3;
#pragma unroll
      for (int j = 0; j < 4; ++j) split3(vlo[j], &t1.s[j], &t2.s[j], &t3.s[j]);
#pragma unroll
      for (int j = 0; j < 4; ++j)
        split3(vhi[j], &t1.s[4 + j], &t2.s[4 + j], &t3.s[4 + j]);
      *(bf16x8*)&As[cur ^ 1][0][ao_st] = t1.v;
      *(bf16x8*)&As[cur ^ 1][1][ao_st] = t2.v;
      *(bf16x8*)&As[cur ^ 1][2][ao_st] = t3.v;
      __syncthreads();
    }
  }

  // ---- epilogue: relu(base + acc) -> Hn_out (NT stores) ----
#pragma unroll
  for (int m = 0; m < 4; ++m) {
    int row0 = a0 + m * 16 + lk * 4;
#pragma unroll
    for (int n = 0; n < 4; ++n) {
      int col = w * 64 + n * 16 + lr;
#pragma unroll
      for (int r = 0; r < 4; ++r) {
        int row = row0 + r;
        if (row < N_ATOMS) {
          size_t off = (size_t)row * HIDDEN + col;
          float v = fmaxf(base[off] + acc[m][n][r], 0.f);
          __builtin_nontemporal_store(v, &Hn_out[off]);
        }
      }
    }
  }
}

// ---------------------------------------------------------------------------
// transpose: out[h][a] = Hn[a][h]; 64x64 tiles; NT stores.
// ---------------------------------------------------------------------------
__global__ __launch_bounds__(256) void transpose_kernel(
    const float* __restrict__ Hn, float* __restrict__ out) {
  __shared__ float tile[64][68];
  int a0 = blockIdx.x * 64, h0 = blockIdx.y * 64;
  int tid = threadIdx.x;
#pragma unroll
  for (int p = 0; p < 2; ++p) {
    int id = tid + p * 256;
    int r = id >> 3, c8 = (id & 7) * 8;
    int ag = a0 + r;
    if (ag > N_ATOMS - 1) ag = N_ATOMS - 1;
    const float* hp = &Hn[(size_t)ag * HIDDEN + h0 + c8];
    *(f32x4*)&tile[r][c8] = *(const f32x4*)hp;
    *(f32x4*)&tile[r][c8 + 4] = *(const f32x4*)(hp + 4);
  }
  __syncthreads();
  int h = tid >> 2, as = (tid & 3) * 16;
  size_t ob = (size_t)(h0 + h) * N_ATOMS + a0 + as;
  if (a0 + 64 <= N_ATOMS) {
#pragma unroll
    for (int q = 0; q < 4; ++q) {
      f32x4 v;
#pragma unroll
      for (int j = 0; j < 4; ++j) v[j] = tile[as + q * 4 + j][h];
      __builtin_nontemporal_store(v, (f32x4*)&out[ob + q * 4]);
    }
  } else {
    for (int j = 0; j < 16; ++j)
      if (a0 + as + j < N_ATOMS)
        __builtin_nontemporal_store(tile[as + j][h], &out[ob + j]);
  }
}

extern "C" void kernel_launch(void* const* d_in, const int* in_sizes, int n_in,
                              void* d_out, int out_size, void* d_ws, size_t ws_size,
                              hipStream_t stream) {
  const float* fatoms = (const float*)d_in[0];
  const float* fbonds = (const float*)d_in[1];
  const int* aoutgraph = (const int*)d_in[2];
  const int* all_bonds = (const int*)d_in[3];
  const float* W_nin = (const float*)d_in[4];
  const float* W_node = (const float*)d_in[5];
  float* out = (float*)d_out;

  const size_t NH = (size_t)N_ATOMS * HIDDEN;
  float* base = (float*)d_ws;        // 102.4 MB
  float* HnA = base + NH;            // 102.4 MB
  short* Bsp = (short*)(HnA + NH);   // 384 KB pre-split W terms
  float* HnB = out;                  // d_out doubles as ping-pong buffer

  split_w_kernel<<<64, 256, 0, stream>>>(W_node, Bsp);
  init_kernel<<<N_ATOMS / 32, 256, 0, stream>>>(fatoms, fbonds, aoutgraph,
                                                W_nin, W_node, HnA, base);

  const int nblk = (N_ATOMS + 63) / 64;  // 1563
  for (int it = 0; it < DEPTH; ++it) {
    const float* in = (it & 1) ? HnB : HnA;
    float* o = (it & 1) ? HnA : HnB;
    fused_kernel<<<nblk, 256, 0, stream>>>(in, base, Bsp, aoutgraph,
                                           all_bonds, o);
  }
  // DEPTH even -> final Hn is in HnA; d_out receives the transpose.
  dim3 tgrid(nblk, HIDDEN / 64);
  transpose_kernel<<<tgrid, 256, 0, stream>>>(HnA, out);
}